// Round 1
// 267.607 us; speedup vs baseline: 1.0242x; 1.0242x over previous
//
#include <hip/hip_runtime.h>
#include <hip/hip_bf16.h>
#include <stdint.h>

// Conv4d B=1 IC=16 OC=32 K=3^4 pad=1 stride=1, D=32 -> implicit GEMM on MFMA.
// Round 4: x pre-packed to bf16 (xpack) by a separate pass; conv stages the
// LDS tile with async global_load_lds dwordx4 (addresses precomputed once,
// OOB lanes -> zero page). Removes the per-block fp32->bf16 conversion VALU
// (was ~22% VALUBusy) and the 8x strided scalar loads per point.
// Compute structure + verified C/D layout identical to round 3.

typedef __bf16 bf16x8 __attribute__((ext_vector_type(8)));
typedef float f32x16 __attribute__((ext_vector_type(16)));

#define X_IC_STRIDE 1048576  // 32^4 elements per ic plane
#define W_K 1296             // 16 * 81
#define WPACK_DWORDS 23040   // 90 frags * 256 dwords (92160 B)
#define XPACK_OFF 98304      // xpack starts here in d_ws (after wpack, aligned)
#define XPACK_BYTES 33554432u // 2^20 points * 32 B ([point][g][16B])
#define ZOFF XPACK_BYTES      // 32 B zero page right after xpack
#define LDS_BYTES (13 * 256 * 16)  // 53248 B (3264 real pts + 64 pad slots)

__device__ __forceinline__ unsigned rne_bf16(float f) {
    unsigned b = __builtin_bit_cast(unsigned, f);
    return (b + 0x7FFFu + ((b >> 16) & 1u)) >> 16;
}

__device__ __forceinline__ void gload_lds16(const unsigned char* g, unsigned char* s) {
    __builtin_amdgcn_global_load_lds(
        (const __attribute__((address_space(1))) unsigned int*)g,
        (__attribute__((address_space(3))) unsigned int*)s, 16, 0, 0);
}

// Pack w[32][1296] fp32 -> wpack: 90 frags of 1024 B.
// frag fi = (g*9 + dadb)*5 + p ; within frag: lane(kh*32+oc)*16B + icpair*4B.
// slot = 2p+kh ; slot 9 = zero pad.
__global__ void pack_w_kernel(const float* __restrict__ w, unsigned* __restrict__ wpack) {
    int D = blockIdx.x * 256 + threadIdx.x;
    if (D >= WPACK_DWORDS) return;
    int t    = D & 3;          // ic pair
    int lane = (D >> 2) & 63;
    int fi   = D >> 8;
    int p    = fi % 5;
    int dadb = (fi / 5) % 9;
    int g    = fi / 45;
    int kh   = lane >> 5;
    int oc   = lane & 31;
    int slot = 2 * p + kh;
    unsigned pk = 0u;
    if (slot < 9) {
        int da = dadb / 3, db = dadb % 3;
        int dc = slot / 3, dd = slot % 3;
        int koff = da * 27 + db * 9 + dc * 3 + dd;
        int ic0  = g * 8 + 2 * t;
        unsigned lo = rne_bf16(w[oc * W_K + ic0 * 81 + koff]);
        unsigned hi = rne_bf16(w[oc * W_K + (ic0 + 1) * 81 + koff]);
        pk = lo | (hi << 16);
    }
    wpack[D] = pk;
}

// Pack x fp32 [16][2^20] -> xpack bf16 [2^20][2 groups][16 B] + 32 B zero page.
// Group g, dword t holds ic pair (g*8+2t, g*8+2t+1) -- matches wpack layout.
__global__ __launch_bounds__(256) void pack_x_kernel(const float* __restrict__ x,
                                                     unsigned char* __restrict__ xpack) {
    unsigned P = blockIdx.x * 256 + threadIdx.x;   // grid = 4096 * 256 = 2^20
    unsigned u[16];
#pragma unroll
    for (int ic = 0; ic < 16; ++ic)
        u[ic] = rne_bf16(x[(size_t)ic * X_IC_STRIDE + P]);
    uint4 lo = make_uint4(u[0] | (u[1] << 16), u[2] | (u[3] << 16),
                          u[4] | (u[5] << 16), u[6] | (u[7] << 16));
    uint4 hi = make_uint4(u[8] | (u[9] << 16), u[10] | (u[11] << 16),
                          u[12] | (u[13] << 16), u[14] | (u[15] << 16));
    *(uint4*)(xpack + (size_t)P * 32) = lo;
    *(uint4*)(xpack + (size_t)P * 32 + 16) = hi;
    if (P == 0) {  // zero page for out-of-range halo points (both g offsets)
        *(uint4*)(xpack + ZOFF) = make_uint4(0u, 0u, 0u, 0u);
        *(uint4*)(xpack + ZOFF + 16) = make_uint4(0u, 0u, 0u, 0u);
    }
}

template <int XP>
__global__ __launch_bounds__(256, 3) void conv4d_mfma(
    const float* __restrict__ x,         // [16][32][32][32][32] (XP=0 path only)
    const unsigned char* __restrict__ wpack,
    const unsigned char* __restrict__ xpack,
    const float* __restrict__ bias,      // [32]
    float* __restrict__ out)             // [32][32][32][32][32]
{
    __shared__ __attribute__((aligned(16))) unsigned char lds[LDS_BYTES];

    const int tid  = threadIdx.x;
    const int lane = tid & 63;
    const int wv   = tid >> 6;     // wave 0..3
    const int kh   = lane >> 5;    // k-half -> slot select
    const int ln   = lane & 31;    // A: oc ; B: d

    // XCD-aware bijective swizzle (2048 blocks % 8 XCDs == 0): each XCD gets a
    // contiguous 256-block chunk -> halo rows of xpack stay in its L2.
    const int bid = blockIdx.x;
    const int blk = ((bid & 7) << 8) | (bid >> 3);
    const int c0  = (blk & 7) * 4;
    const int b0  = ((blk >> 3) & 15) * 2;
    const int a0  = (blk >> 7) * 2;
    const int ai  = wv >> 1, bi = wv & 1;

    // per-lane b-frag bases: slot = 2p+kh -> (dc,dd); dummy slot 9 -> (2,2) (x *0-weight)
    int pbase[5];
#pragma unroll
    for (int p = 0; p < 5; ++p) {
        int slot = 2 * p + kh;
        int dc = (slot >= 9) ? 2 : slot / 3;
        int dd = (slot >= 9) ? 2 : slot % 3;
        pbase[p] = dc * 544 + (ln + dd) * 16;
    }

    // Precompute per-thread staging source offsets once (shared by both g phases;
    // layout [point][g][16B] makes the g adjustment a constant +16 B).
    unsigned xoff[13];
    if (XP) {
#pragma unroll
        for (int it = 0; it < 13; ++it) {
            int t   = tid + it * 256;
            int dpr = t % 34;
            int row = t / 34;
            int rc = row % 6; int r2 = row / 6;
            int rb = r2 & 3;  int ra = r2 >> 2;
            int a_in = a0 + ra - 1, b_in = b0 + rb - 1;
            int c_in = c0 + rc - 1, d_in = dpr - 1;
            bool v = ((unsigned)a_in < 32u) & ((unsigned)b_in < 32u) &
                     ((unsigned)c_in < 32u) & ((unsigned)d_in < 32u);
            unsigned P = (unsigned)(((a_in * 32 + b_in) * 32 + c_in) * 32 + d_in);
            xoff[it] = v ? P * 32u : ZOFF;
        }
    }

    f32x16 acc[4];
#pragma unroll
    for (int ci = 0; ci < 4; ++ci)
#pragma unroll
        for (int r = 0; r < 16; ++r) acc[ci][r] = 0.f;

    // ---- prime a-frag register buffer for fi=0 ----
    bf16x8 af[5];
#pragma unroll
    for (int p = 0; p < 5; ++p)
        af[p] = *(const bf16x8*)(wpack + (size_t)p * 1024 + lane * 16);

    for (int g = 0; g < 2; ++g) {
        if (g) __syncthreads();  // protect LDS before restage
        if (XP) {
            // ---- async stage: 13 global_load_lds dwordx4 per thread-slot ----
            // LDS dest is linear in t (wave-uniform base + lane*16 semantics).
            const int gofs = g << 4;
#pragma unroll
            for (int it = 0; it < 13; ++it)
                gload_lds16(xpack + xoff[it] + gofs,
                            lds + ((it * 256 + (wv << 6)) << 4));
        } else {
            // ---- legacy stage: convert fp32->bf16 on the fly ----
            for (int t = tid; t < 96 * 34; t += 256) {
                int dpr = t % 34;
                int row = t / 34;
                int rc = row % 6; int r2 = row / 6;
                int rb = r2 & 3;  int ra = r2 >> 2;
                int a_in = a0 + ra - 1, b_in = b0 + rb - 1;
                int c_in = c0 + rc - 1, d_in = dpr - 1;
                uint4 pk = make_uint4(0u, 0u, 0u, 0u);
                if ((unsigned)a_in < 32u && (unsigned)b_in < 32u &&
                    (unsigned)c_in < 32u && (unsigned)d_in < 32u) {
                    const float* xp = x + (size_t)(g * 8) * X_IC_STRIDE +
                                      (((a_in * 32 + b_in) * 32 + c_in) * 32 + d_in);
                    unsigned u[8];
#pragma unroll
                    for (int j = 0; j < 8; ++j)
                        u[j] = rne_bf16(xp[j * X_IC_STRIDE]);
                    pk.x = u[0] | (u[1] << 16); pk.y = u[2] | (u[3] << 16);
                    pk.z = u[4] | (u[5] << 16); pk.w = u[6] | (u[7] << 16);
                }
                *(uint4*)(lds + t * 16) = pk;
            }
        }
        __syncthreads();  // compiler drains vmcnt(0) here -> staged tile visible

        for (int dadb = 0; dadb < 9; ++dadb) {
            const int fi  = g * 9 + dadb;
            const int nfi = (fi + 1 > 17) ? 17 : fi + 1;
            // prefetch next phase's a-frags (register double buffer, L2-hot)
            bf16x8 afn[5];
#pragma unroll
            for (int p = 0; p < 5; ++p)
                afn[p] = *(const bf16x8*)(wpack + ((size_t)nfi * 5 + p) * 1024 + lane * 16);

            const int da = dadb / 3, db = dadb % 3;
            const int ubase = ((ai + da) * 24 + (bi + db) * 6) * 544;
#pragma unroll
            for (int p = 0; p < 5; ++p) {
                const unsigned char* bp = lds + ubase + pbase[p];
#pragma unroll
                for (int ci = 0; ci < 4; ++ci) {
                    bf16x8 bfrag = *(const bf16x8*)(bp + ci * 544);
                    acc[ci] = __builtin_amdgcn_mfma_f32_32x32x16_bf16(
                        af[p], bfrag, acc[ci], 0, 0, 0);
                }
            }
#pragma unroll
            for (int p = 0; p < 5; ++p) af[p] = afn[p];
        }
    }

    // epilogue: D col = lane&31 = d (coalesced), row = oc = (r&3)+8*(r>>2)+4*kh
    float bv[16];
#pragma unroll
    for (int r = 0; r < 16; ++r) bv[r] = bias[(r & 3) + 8 * (r >> 2) + 4 * kh];

    const size_t sp_base = (((size_t)(a0 + ai) * 32 + (b0 + bi)) * 32 + c0);
#pragma unroll
    for (int ci = 0; ci < 4; ++ci) {
#pragma unroll
        for (int r = 0; r < 16; ++r) {
            int oc_ = (r & 3) + 8 * (r >> 2) + 4 * kh;
            out[(size_t)oc_ * X_IC_STRIDE + (sp_base + ci) * 32 + ln] = acc[ci][r] + bv[r];
        }
    }
}

extern "C" void kernel_launch(void* const* d_in, const int* in_sizes, int n_in,
                              void* d_out, int out_size, void* d_ws, size_t ws_size,
                              hipStream_t stream) {
    const float* x    = (const float*)d_in[0];
    const float* w    = (const float*)d_in[1];
    const float* bias = (const float*)d_in[2];
    float* out        = (float*)d_out;
    unsigned* wpack   = (unsigned*)d_ws;                       // 92160 B
    unsigned char* xpack = (unsigned char*)d_ws + XPACK_OFF;   // 32 MiB + 32 B

    pack_w_kernel<<<dim3((WPACK_DWORDS + 255) / 256), dim3(256), 0, stream>>>(w, wpack);
    if (ws_size >= (size_t)XPACK_OFF + XPACK_BYTES + 32) {
        pack_x_kernel<<<dim3(4096), dim3(256), 0, stream>>>(x, xpack);
        conv4d_mfma<1><<<dim3(2048), dim3(256), 0, stream>>>(
            x, (const unsigned char*)d_ws, xpack, bias, out);
    } else {
        conv4d_mfma<0><<<dim3(2048), dim3(256), 0, stream>>>(
            x, (const unsigned char*)d_ws, xpack, bias, out);
    }
}